// Round 1
// baseline (1754.841 us; speedup 1.0000x reference)
//
#include <hip/hip_runtime.h>

namespace {

constexpr int B     = 512;
constexpr int IN_F  = 784;
constexpr int E     = 512;
constexpr int ABSZ  = 16;   // A * BSZ
constexpr int J     = 7;
constexpr int NC    = 128;
constexpr int NT    = 256;  // threads per workgroup

// out[o] = relu?(bias[o] + sum_e vin[e] * W[e*E + o]) for o = 2*tid, 2*tid+1
__device__ inline void matvec512(const float* __restrict__ W,
                                 const float* __restrict__ bias,
                                 const float* __restrict__ vin,
                                 float* __restrict__ vout,
                                 int tid, bool do_relu)
{
    const int o = 2 * tid;
    float a0 = 0.f, a1 = 0.f;
    const float* wp = W + o;
    #pragma unroll 8
    for (int e = 0; e < E; ++e) {
        const float v = vin[e];
        const float2 w = *reinterpret_cast<const float2*>(wp + (size_t)e * E);
        a0 = fmaf(v, w.x, a0);
        a1 = fmaf(v, w.y, a1);
    }
    a0 += bias[o];
    a1 += bias[o + 1];
    if (do_relu) { a0 = fmaxf(a0, 0.f); a1 = fmaxf(a1, 0.f); }
    vout[o]     = a0;
    vout[o + 1] = a1;
}

// Computes flat block index from address transform of vin, given current idx.
__device__ inline int next_address(const float* __restrict__ ad_W1,
                                   const float* __restrict__ ad_b1,
                                   const float* __restrict__ ad_W2,
                                   const float* __restrict__ ad_b2,
                                   int idx,
                                   const float* __restrict__ vin,
                                   float* __restrict__ s_h,
                                   float* __restrict__ s_part,
                                   float* __restrict__ s_logits,
                                   int* __restrict__ s_idx_p,
                                   int tid)
{
    // h = relu(vin @ ad_W1[idx] + ad_b1[idx])
    matvec512(ad_W1 + (size_t)idx * E * E, ad_b1 + (size_t)idx * E, vin, s_h, tid, true);
    __syncthreads();

    // logits[o] = sum_e h[e] * ad_W2[idx][e][o] + ad_b2[idx][o]
    // 16 threads per logit, e-strided; partials reduced via LDS.
    {
        const int o  = tid & (ABSZ - 1);
        const int e0 = tid >> 4;  // 0..15
        const float* w2 = ad_W2 + (size_t)idx * E * ABSZ;
        float acc = 0.f;
        #pragma unroll 4
        for (int e = e0; e < E; e += 16) {
            acc = fmaf(s_h[e], w2[(size_t)e * ABSZ + o], acc);
        }
        s_part[tid] = acc;
    }
    __syncthreads();
    if (tid < ABSZ) {
        float sum = ad_b2[(size_t)idx * ABSZ + tid];
        #pragma unroll
        for (int k = 0; k < 16; ++k) sum += s_part[tid + 16 * k];
        s_logits[tid] = sum;
    }
    __syncthreads();
    if (tid == 0) {
        int a0 = 0, a1 = 0;
        float m0 = s_logits[0], m1 = s_logits[8];
        #pragma unroll
        for (int k = 1; k < 8; ++k) {
            if (s_logits[k]     > m0) { m0 = s_logits[k];     a0 = k; }
            if (s_logits[8 + k] > m1) { m1 = s_logits[8 + k]; a1 = k; }
        }
        *s_idx_p = a0 * 8 + a1;   // strides = [8, 1]
    }
    __syncthreads();
    return *s_idx_p;
}

// s_t = relu(relu(s_state@W1+b1)@W2+b2) / (||s_state|| + 1e-6)
__device__ inline void through_block(const float* __restrict__ st_W1,
                                     const float* __restrict__ st_b1,
                                     const float* __restrict__ st_W2,
                                     const float* __restrict__ st_b2,
                                     int idx,
                                     const float* __restrict__ s_state,
                                     float* __restrict__ s_h,
                                     float* __restrict__ s_t,
                                     float* __restrict__ s_part,
                                     float* __restrict__ s_scale,
                                     int tid)
{
    matvec512(st_W1 + (size_t)idx * E * E, st_b1 + (size_t)idx * E, s_state, s_h, tid, true);

    // sum of squares of s_state (input state), wave-reduced
    {
        const int o = 2 * tid;
        float v0 = s_state[o], v1 = s_state[o + 1];
        float ss = v0 * v0 + v1 * v1;
        #pragma unroll
        for (int off = 32; off > 0; off >>= 1) ss += __shfl_down(ss, off, 64);
        if ((tid & 63) == 0) s_part[tid >> 6] = ss;
    }
    __syncthreads();   // s_h complete + s_part complete
    if (tid == 0) {
        float tot = s_part[0] + s_part[1] + s_part[2] + s_part[3];
        *s_scale = 1.0f / (sqrtf(tot) + 1e-6f);
    }
    matvec512(st_W2 + (size_t)idx * E * E, st_b2 + (size_t)idx * E, s_h, s_t, tid, true);
    __syncthreads();   // s_t complete + s_scale written
    {
        const float sc = *s_scale;
        const int o = 2 * tid;
        s_t[o]     *= sc;
        s_t[o + 1] *= sc;
    }
    __syncthreads();   // s_t normalized, visible to all
}

__global__ __launch_bounds__(NT) void brain_kernel(
    const float* __restrict__ x,
    const float* __restrict__ emb_W,  const float* __restrict__ emb_b,
    const float* __restrict__ st_W1,  const float* __restrict__ st_b1,
    const float* __restrict__ st_W2,  const float* __restrict__ st_b2,
    const float* __restrict__ ad_W1,  const float* __restrict__ ad_b1,
    const float* __restrict__ ad_W2,  const float* __restrict__ ad_b2,
    const float* __restrict__ out_W1, const float* __restrict__ out_b1,
    const float* __restrict__ out_W2, const float* __restrict__ out_b2,
    float* __restrict__ out)
{
    const int b   = blockIdx.x;
    const int tid = threadIdx.x;

    __shared__ float s_x[IN_F];
    __shared__ float s_state[E];
    __shared__ float s_init[E];
    __shared__ float s_h[E];
    __shared__ float s_t[E];
    __shared__ float s_part[NT];
    __shared__ float s_logits[ABSZ];
    __shared__ float s_scale;
    __shared__ int   s_idx;

    // stage x row
    for (int i = tid; i < IN_F; i += NT) s_x[i] = x[(size_t)b * IN_F + i];
    __syncthreads();

    // embedding: state = x @ emb_W + emb_b
    {
        const int o = 2 * tid;
        float a0 = 0.f, a1 = 0.f;
        const float* wp = emb_W + o;
        #pragma unroll 4
        for (int i = 0; i < IN_F; ++i) {
            const float v = s_x[i];
            const float2 w = *reinterpret_cast<const float2*>(wp + (size_t)i * E);
            a0 = fmaf(v, w.x, a0);
            a1 = fmaf(v, w.y, a1);
        }
        a0 += emb_b[o];
        a1 += emb_b[o + 1];
        s_state[o]     = a0;  s_state[o + 1] = a1;
        s_init[o]      = a0;  s_init[o + 1]  = a1;
    }
    __syncthreads();

    // initial address from block 0, on initial_state
    int idx = next_address(ad_W1, ad_b1, ad_W2, ad_b2, 0, s_init,
                           s_h, s_part, s_logits, &s_idx, tid);

    for (int i = 0; i < J; ++i) {
        through_block(st_W1, st_b1, st_W2, st_b2, idx,
                      s_state, s_h, s_t, s_part, &s_scale, tid);
        const int nidx = next_address(ad_W1, ad_b1, ad_W2, ad_b2, idx, s_t,
                                      s_h, s_part, s_logits, &s_idx, tid);
        // state = t + (i/6) * initial_state
        {
            const float ramp = (float)i * (1.0f / 6.0f);
            const int o = 2 * tid;
            s_state[o]     = s_t[o]     + ramp * s_init[o];
            s_state[o + 1] = s_t[o + 1] + ramp * s_init[o + 1];
        }
        __syncthreads();
        idx = nidx;
    }

    // final = through_block(state, idx) + initial_state
    through_block(st_W1, st_b1, st_W2, st_b2, idx,
                  s_state, s_h, s_t, s_part, &s_scale, tid);
    {
        const int o = 2 * tid;
        s_state[o]     = s_t[o]     + s_init[o];
        s_state[o + 1] = s_t[o + 1] + s_init[o + 1];
    }
    __syncthreads();

    // h = relu(final @ out_W1 + out_b1)
    matvec512(out_W1, out_b1, s_state, s_h, tid, true);
    __syncthreads();

    // out = h @ out_W2 + out_b2   (out_W2: [E, NC])
    {
        const int oo = tid & (NC - 1);
        const int e0 = tid >> 7;   // 0 or 1
        float acc = 0.f;
        #pragma unroll 4
        for (int e = e0; e < E; e += 2) {
            acc = fmaf(s_h[e], out_W2[(size_t)e * NC + oo], acc);
        }
        s_part[tid] = acc;
    }
    __syncthreads();
    if (tid < NC) {
        out[(size_t)b * NC + tid] = out_b2[tid] + s_part[tid] + s_part[tid + NC];
    }
}

}  // namespace

extern "C" void kernel_launch(void* const* d_in, const int* in_sizes, int n_in,
                              void* d_out, int out_size, void* d_ws, size_t ws_size,
                              hipStream_t stream)
{
    const float* x      = (const float*)d_in[0];
    const float* emb_W  = (const float*)d_in[1];
    const float* emb_b  = (const float*)d_in[2];
    const float* st_W1  = (const float*)d_in[3];
    const float* st_b1  = (const float*)d_in[4];
    const float* st_W2  = (const float*)d_in[5];
    const float* st_b2  = (const float*)d_in[6];
    const float* ad_W1  = (const float*)d_in[7];
    const float* ad_b1  = (const float*)d_in[8];
    const float* ad_W2  = (const float*)d_in[9];
    const float* ad_b2  = (const float*)d_in[10];
    const float* out_W1 = (const float*)d_in[11];
    const float* out_b1 = (const float*)d_in[12];
    const float* out_W2 = (const float*)d_in[13];
    const float* out_b2 = (const float*)d_in[14];
    float* out = (float*)d_out;

    hipLaunchKernelGGL(brain_kernel, dim3(B), dim3(NT), 0, stream,
                       x, emb_W, emb_b, st_W1, st_b1, st_W2, st_b2,
                       ad_W1, ad_b1, ad_W2, ad_b2,
                       out_W1, out_b1, out_W2, out_b2, out);
}